// Round 6
// baseline (895.882 us; speedup 1.0000x reference)
//
#include <hip/hip_runtime.h>
#include <stdint.h>

typedef __bf16 bf16;
typedef __attribute__((ext_vector_type(8))) __bf16 bf16x8;
typedef __attribute__((ext_vector_type(4))) float f32x4;

#define LORA_SCALE 0.25f

// async global->LDS, 16B per lane. LDS dest is wave-uniform base + lane*16.
__device__ __forceinline__ void gload_lds16(const bf16* g, bf16* l) {
    __builtin_amdgcn_global_load_lds(
        (const __attribute__((address_space(1))) uint32_t*)g,
        (__attribute__((address_space(3))) uint32_t*)l,
        16, 0, 0);
}

__device__ __forceinline__ bf16x8 cvt8(const float* p) {
    f32x4 a = *(const f32x4*)p;
    f32x4 b = *(const f32x4*)(p + 4);
    bf16x8 r;
    r[0] = (bf16)a[0]; r[1] = (bf16)a[1]; r[2] = (bf16)a[2]; r[3] = (bf16)a[3];
    r[4] = (bf16)b[0]; r[5] = (bf16)b[1]; r[6] = (bf16)b[2]; r[7] = (bf16)b[3];
    return r;
}

// f32 -> bf16 elementwise, 8 elems/thread. n must be a multiple of 2048.
__global__ __launch_bounds__(256)
void cvt_f32_bf16(const float* __restrict__ in, bf16* __restrict__ out) {
    const int idx = (blockIdx.x * 256 + threadIdx.x) * 8;
    *(bf16x8*)&out[idx] = cvt8(&in[idx]);
}

// t1[m][r] = sum_k X[m][k] * Aall[aid][r][k]. 4 rows per wave (amortizes the
// A-row loads 4x). Also writes Xb = bf16(X) and zeroes T2 (for GEMM1's
// fused-atomic t2 accumulation). K=1024. Grid: M/16 blocks of 256.
__global__ __launch_bounds__(256)
void lora1(const float* __restrict__ X, const float* __restrict__ Aall,
           const int* __restrict__ adapter, float* __restrict__ T,
           bf16* __restrict__ Xb, float* __restrict__ T2, int M)
{
    const int K = 1024;
    // zero T2 [M][4]
    const int gid = blockIdx.x * 256 + threadIdx.x;
    if (gid < M) {
        f32x4 z; z[0] = 0.f; z[1] = 0.f; z[2] = 0.f; z[3] = 0.f;
        *(f32x4*)&T2[(int64_t)gid * 4] = z;
    }

    const int aid = adapter[0];
    const float* Aa = Aall + (int64_t)aid * 4 * K;
    const int wid  = gid >> 6;          // 0 .. M/4-1
    const int lane = threadIdx.x & 63;
    const int m0   = wid * 4;

    float acc[4][4];
    #pragma unroll
    for (int rr = 0; rr < 4; rr++)
        #pragma unroll
        for (int r = 0; r < 4; r++) acc[rr][r] = 0.f;

    #pragma unroll
    for (int it = 0; it < K / 512; it++) {
        const int k = it * 512 + lane * 8;
        float av[4][8];
        #pragma unroll
        for (int r = 0; r < 4; r++) {
            f32x4 a = *(const f32x4*)&Aa[r * K + k];
            f32x4 b = *(const f32x4*)&Aa[r * K + k + 4];
            av[r][0]=a[0]; av[r][1]=a[1]; av[r][2]=a[2]; av[r][3]=a[3];
            av[r][4]=b[0]; av[r][5]=b[1]; av[r][6]=b[2]; av[r][7]=b[3];
        }
        #pragma unroll
        for (int rr = 0; rr < 4; rr++) {
            const float* xp = X + (int64_t)(m0 + rr) * K + k;
            f32x4 a = *(const f32x4*)xp;
            f32x4 b = *(const f32x4*)(xp + 4);
            float xv[8] = {a[0],a[1],a[2],a[3],b[0],b[1],b[2],b[3]};
            bf16x8 xb;
            #pragma unroll
            for (int e = 0; e < 8; e++) xb[e] = (bf16)xv[e];
            *(bf16x8*)&Xb[(int64_t)(m0 + rr) * K + k] = xb;
            #pragma unroll
            for (int r = 0; r < 4; r++)
                #pragma unroll
                for (int e = 0; e < 8; e++)
                    acc[rr][r] += xv[e] * av[r][e];
        }
    }
    #pragma unroll
    for (int rr = 0; rr < 4; rr++)
        #pragma unroll
        for (int r = 0; r < 4; r++)
            #pragma unroll
            for (int off = 32; off >= 1; off >>= 1)
                acc[rr][r] += __shfl_xor(acc[rr][r], off);
    if (lane == 0) {
        #pragma unroll
        for (int rr = 0; rr < 4; rr++) {
            f32x4 t;
            t[0] = acc[rr][0]; t[1] = acc[rr][1]; t[2] = acc[rr][2]; t[3] = acc[rr][3];
            *(f32x4*)&T[(int64_t)(m0 + rr) * 4] = t;
        }
    }
}

// C[m][n] = act( sum_k A[m][k]*Bm[n][k] + SCALE * sum_r Tlo[m][r]*Blo[aid][n][r] )
// Block tile 256x128, BK=64; 4 waves (2x2), each wave 128x64 (8x4 of 16x16x32
// MFMA). global_load_lds width-16 staging with XOR K-chunk swizzle.
// PART: 0 = partition N across XCDs (n-fastest within), 1 = partition M.
// FUSET2: accumulate T2[m][r2] += sum_n C[m][n]*A2[aid][r2][n] via atomics.
template<bool RELU, typename CT, int PART, bool FUSET2>
__global__ __launch_bounds__(256, 3)
void gemm_lora(const bf16* __restrict__ A,    // [M][K] bf16
               const bf16* __restrict__ Bm,   // [N][K] bf16 (torch [out,in])
               CT* __restrict__ C,            // [M][N]
               const float* __restrict__ Tlo, // [M][4]
               const float* __restrict__ Blo, // [NUM][N][4] f32
               const int* __restrict__ adapter,
               const float* __restrict__ A2,  // [NUM][4][N] f32 (FUSET2)
               float* __restrict__ T2,        // [M][4] (FUSET2)
               int M, int N, int K)
{
    __shared__ bf16 smem[256 * 64 + 128 * 64];   // 48 KB
    bf16* sA = smem;                              // [256][64]
    bf16* sB = smem + 256 * 64;                   // [128][64]

    const int tid  = threadIdx.x;
    const int lane = tid & 63;
    const int w    = tid >> 6;
    const int quad = lane >> 4;
    const int l16  = lane & 15;

    // XCD-aware remap (consecutive dispatch ids round-robin across 8 XCDs).
    int bx, by;
    {
        const int Nt = gridDim.x, Mt = gridDim.y;
        const int id = blockIdx.y * Nt + blockIdx.x;
        const int xcd = id & 7, k = id >> 3;
        if (PART == 0) { const int q = Nt >> 3; bx = xcd * q + (k % q); by = k / q; }
        else           { const int q = Mt >> 3; bx = k % Nt; by = xcd * q + (k / Nt); }
    }
    const int nBase = bx * 128;
    const int mBase = by * 256;
    const int wm = (w >> 1) * 128;               // 0 or 128
    const int wn = (w & 1) * 64;                 // 0 or 64

    f32x4 acc[8][4];
    #pragma unroll
    for (int i = 0; i < 8; i++)
        #pragma unroll
        for (int j = 0; j < 4; j++)
            #pragma unroll
            for (int e = 0; e < 4; e++)
                acc[i][j][e] = 0.f;

    const bf16* gA = A  + (int64_t)mBase * K;
    const bf16* gB = Bm + (int64_t)nBase * K;
    const int ldRow  = tid >> 3;                 // 0..31
    const int swzCol = ((tid & 7) ^ ((tid >> 3) & 7)) * 8;

    for (int kt = 0; kt < K; kt += 64) {
        #pragma unroll
        for (int i = 0; i < 8; i++)
            gload_lds16(gA + (int64_t)(i * 32 + ldRow) * K + kt + swzCol,
                        sA + (i * 32 + w * 8) * 64);
        #pragma unroll
        for (int i = 0; i < 4; i++)
            gload_lds16(gB + (int64_t)(i * 32 + ldRow) * K + kt + swzCol,
                        sB + (i * 32 + w * 8) * 64);
        __syncthreads();
        #pragma unroll
        for (int ks = 0; ks < 2; ks++) {
            const int kpos = (((ks * 4 + quad) ^ (l16 & 7))) * 8;
            bf16x8 af[8], bfv[4];
            #pragma unroll
            for (int i = 0; i < 8; i++)
                af[i] = *(const bf16x8*)&sA[(wm + i * 16 + l16) * 64 + kpos];
            #pragma unroll
            for (int j = 0; j < 4; j++)
                bfv[j] = *(const bf16x8*)&sB[(wn + j * 16 + l16) * 64 + kpos];
            #pragma unroll
            for (int i = 0; i < 8; i++)
                #pragma unroll
                for (int j = 0; j < 4; j++)
                    acc[i][j] = __builtin_amdgcn_mfma_f32_16x16x32_bf16(af[i], bfv[j], acc[i][j], 0, 0, 0);
        }
        __syncthreads();
    }

    // Epilogue
    const int aid = adapter[0];
    const float* Ba = Blo + (int64_t)aid * N * 4;

    f32x4 bv[4];
    #pragma unroll
    for (int j = 0; j < 4; j++) {
        const int f = nBase + wn + j * 16 + l16;
        bv[j] = *(const f32x4*)&Ba[(int64_t)f * 4];
    }

    // A2 columns for this lane (FUSET2): a2v[j][r2] = A2a[r2][nBase+wn+j*16+l16]
    float a2v[4][4];
    if (FUSET2) {
        const float* A2a = A2 + (int64_t)aid * 4 * N;
        #pragma unroll
        for (int j = 0; j < 4; j++) {
            const int f = nBase + wn + j * 16 + l16;
            #pragma unroll
            for (int r2 = 0; r2 < 4; r2++)
                a2v[j][r2] = A2a[(int64_t)r2 * N + f];
        }
    }

    if constexpr (sizeof(CT) == 2) {
        bf16* scratch = smem + w * (64 * 72);
        #pragma unroll
        for (int g = 0; g < 2; g++) {
            #pragma unroll
            for (int mi2 = 0; mi2 < 4; mi2++) {
                const int mi = g * 4 + mi2;
                f32x4 tv[4];
                #pragma unroll
                for (int r = 0; r < 4; r++) {
                    const int m = mBase + wm + mi * 16 + quad * 4 + r;
                    tv[r] = *(const f32x4*)&Tlo[(int64_t)m * 4];
                }
                float tp[4][4];   // [r][r2] partial t2 contributions
                if (FUSET2)
                    #pragma unroll
                    for (int r = 0; r < 4; r++)
                        #pragma unroll
                        for (int r2 = 0; r2 < 4; r2++) tp[r][r2] = 0.f;
                #pragma unroll
                for (int j = 0; j < 4; j++) {
                    #pragma unroll
                    for (int r = 0; r < 4; r++) {
                        const float d = tv[r][0] * bv[j][0] + tv[r][1] * bv[j][1]
                                      + tv[r][2] * bv[j][2] + tv[r][3] * bv[j][3];
                        float v = acc[mi][j][r] + LORA_SCALE * d;
                        if (RELU) v = v > 0.f ? v : 0.f;
                        if (FUSET2)
                            #pragma unroll
                            for (int r2 = 0; r2 < 4; r2++)
                                tp[r][r2] += v * a2v[j][r2];
                        scratch[(mi2 * 16 + quad * 4 + r) * 72 + j * 16 + l16] = (bf16)v;
                    }
                }
                if (FUSET2) {
                    #pragma unroll
                    for (int r = 0; r < 4; r++)
                        #pragma unroll
                        for (int r2 = 0; r2 < 4; r2++)
                            #pragma unroll
                            for (int off = 8; off >= 1; off >>= 1)
                                tp[r][r2] += __shfl_xor(tp[r][r2], off);
                    if (l16 == 0) {
                        #pragma unroll
                        for (int r = 0; r < 4; r++) {
                            const int m = mBase + wm + mi * 16 + quad * 4 + r;
                            #pragma unroll
                            for (int r2 = 0; r2 < 4; r2++)
                                atomicAdd(&T2[(int64_t)m * 4 + r2], tp[r][r2]);
                        }
                    }
                }
            }
            #pragma unroll
            for (int p = 0; p < 8; p++) {
                const int row = p * 8 + (lane >> 3);
                bf16x8 vv = *(const bf16x8*)&scratch[row * 72 + (lane & 7) * 8];
                const int m = mBase + wm + g * 64 + row;
                *(bf16x8*)&C[(int64_t)m * N + nBase + wn + (lane & 7) * 8] = vv;
            }
        }
    } else {
        #pragma unroll
        for (int mi = 0; mi < 8; mi++) {
            f32x4 tv[4];
            #pragma unroll
            for (int r = 0; r < 4; r++) {
                const int m = mBase + wm + mi * 16 + quad * 4 + r;
                tv[r] = *(const f32x4*)&Tlo[(int64_t)m * 4];
            }
            #pragma unroll
            for (int j = 0; j < 4; j++) {
                #pragma unroll
                for (int r = 0; r < 4; r++) {
                    const float d = tv[r][0] * bv[j][0] + tv[r][1] * bv[j][1]
                                  + tv[r][2] * bv[j][2] + tv[r][3] * bv[j][3];
                    float v = acc[mi][j][r] + LORA_SCALE * d;
                    if (RELU) v = v > 0.f ? v : 0.f;
                    const int m = mBase + wm + mi * 16 + quad * 4 + r;
                    C[(int64_t)m * N + nBase + wn + j * 16 + l16] = v;
                }
            }
        }
    }
}

extern "C" void kernel_launch(void* const* d_in, const int* in_sizes, int n_in,
                              void* d_out, int out_size, void* d_ws, size_t ws_size,
                              hipStream_t stream) {
    const float* x  = (const float*)d_in[0];
    const float* W1 = (const float*)d_in[1];
    const float* A1 = (const float*)d_in[2];
    const float* B1 = (const float*)d_in[3];
    const float* W2 = (const float*)d_in[4];
    const float* A2 = (const float*)d_in[5];
    const float* B2 = (const float*)d_in[6];
    const int* adapter = (const int*)d_in[7];
    float* out = (float*)d_out;

    const int M = 16384, D = 1024, F = 4096;

    bf16*  h  = (bf16*)d_ws;                       // M*F bf16 = 128 MiB
    bf16*  xb = h + (size_t)M * F;                 // M*D bf16 =  32 MiB
    bf16*  wb = xb + (size_t)M * D;                // F*D bf16 =   8 MiB (W1b then W2b)
    float* t1 = (float*)(wb + (size_t)F * D);
    float* t2 = t1 + (size_t)M * 4;

    // t1 = x @ A1a^T ; xb = bf16(x) ; t2 = 0
    lora1<<<M / 16, 256, 0, stream>>>(x, A1, adapter, t1, xb, t2, M);
    // wb = bf16(W1)
    cvt_f32_bf16<<<(F * D) / 2048, 256, 0, stream>>>(W1, wb);
    // h = relu(xb @ wb^T + scale * t1 @ B1a^T); t2 += h @ A2a^T (fused)
    dim3 g1(F / 128, M / 256);
    gemm_lora<true, bf16, 0, true><<<g1, 256, 0, stream>>>(
        xb, wb, h, t1, B1, adapter, A2, t2, M, F, D);
    // wb = bf16(W2)
    cvt_f32_bf16<<<(D * F) / 2048, 256, 0, stream>>>(W2, wb);
    // out = h @ wb^T + scale * t2 @ B2a^T  -> f32
    dim3 g2(D / 128, M / 256);
    gemm_lora<false, float, 1, false><<<g2, 256, 0, stream>>>(
        h, wb, out, t2, B2, adapter, nullptr, nullptr, M, D, F);
}

// Round 7
// 844.990 us; speedup vs baseline: 1.0602x; 1.0602x over previous
//
#include <hip/hip_runtime.h>
#include <stdint.h>

typedef __bf16 bf16;
typedef __attribute__((ext_vector_type(8))) __bf16 bf16x8;
typedef __attribute__((ext_vector_type(4))) float f32x4;

#define LORA_SCALE 0.25f

// async global->LDS, 16B per lane. LDS dest is wave-uniform base + lane*16.
__device__ __forceinline__ void gload_lds16(const bf16* g, bf16* l) {
    __builtin_amdgcn_global_load_lds(
        (const __attribute__((address_space(1))) uint32_t*)g,
        (__attribute__((address_space(3))) uint32_t*)l,
        16, 0, 0);
}

__device__ __forceinline__ bf16x8 cvt8(const float* p) {
    f32x4 a = *(const f32x4*)p;
    f32x4 b = *(const f32x4*)(p + 4);
    bf16x8 r;
    r[0] = (bf16)a[0]; r[1] = (bf16)a[1]; r[2] = (bf16)a[2]; r[3] = (bf16)a[3];
    r[4] = (bf16)b[0]; r[5] = (bf16)b[1]; r[6] = (bf16)b[2]; r[7] = (bf16)b[3];
    return r;
}

// f32 -> bf16 elementwise, 8 elems/thread. n must be a multiple of 2048.
__global__ __launch_bounds__(256)
void cvt_f32_bf16(const float* __restrict__ in, bf16* __restrict__ out) {
    const int idx = (blockIdx.x * 256 + threadIdx.x) * 8;
    *(bf16x8*)&out[idx] = cvt8(&in[idx]);
}

// t1[m][r] = sum_k X[m][k] * Aall[aid][r][k]. 4 rows per wave. Also writes
// Xb = bf16(X) and zeroes T2. K=1024. Grid: M/16 blocks of 256.
__global__ __launch_bounds__(256)
void lora1(const float* __restrict__ X, const float* __restrict__ Aall,
           const int* __restrict__ adapter, float* __restrict__ T,
           bf16* __restrict__ Xb, float* __restrict__ T2, int M)
{
    const int K = 1024;
    const int gid = blockIdx.x * 256 + threadIdx.x;
    if (gid < M) {
        f32x4 z; z[0] = 0.f; z[1] = 0.f; z[2] = 0.f; z[3] = 0.f;
        *(f32x4*)&T2[(int64_t)gid * 4] = z;
    }

    const int aid = adapter[0];
    const float* Aa = Aall + (int64_t)aid * 4 * K;
    const int wid  = gid >> 6;
    const int lane = threadIdx.x & 63;
    const int m0   = wid * 4;

    float acc[4][4];
    #pragma unroll
    for (int rr = 0; rr < 4; rr++)
        #pragma unroll
        for (int r = 0; r < 4; r++) acc[rr][r] = 0.f;

    #pragma unroll
    for (int it = 0; it < K / 512; it++) {
        const int k = it * 512 + lane * 8;
        float av[4][8];
        #pragma unroll
        for (int r = 0; r < 4; r++) {
            f32x4 a = *(const f32x4*)&Aa[r * K + k];
            f32x4 b = *(const f32x4*)&Aa[r * K + k + 4];
            av[r][0]=a[0]; av[r][1]=a[1]; av[r][2]=a[2]; av[r][3]=a[3];
            av[r][4]=b[0]; av[r][5]=b[1]; av[r][6]=b[2]; av[r][7]=b[3];
        }
        #pragma unroll
        for (int rr = 0; rr < 4; rr++) {
            const float* xp = X + (int64_t)(m0 + rr) * K + k;
            f32x4 a = *(const f32x4*)xp;
            f32x4 b = *(const f32x4*)(xp + 4);
            float xv[8] = {a[0],a[1],a[2],a[3],b[0],b[1],b[2],b[3]};
            bf16x8 xb;
            #pragma unroll
            for (int e = 0; e < 8; e++) xb[e] = (bf16)xv[e];
            *(bf16x8*)&Xb[(int64_t)(m0 + rr) * K + k] = xb;
            #pragma unroll
            for (int r = 0; r < 4; r++)
                #pragma unroll
                for (int e = 0; e < 8; e++)
                    acc[rr][r] += xv[e] * av[r][e];
        }
    }
    #pragma unroll
    for (int rr = 0; rr < 4; rr++)
        #pragma unroll
        for (int r = 0; r < 4; r++)
            #pragma unroll
            for (int off = 32; off >= 1; off >>= 1)
                acc[rr][r] += __shfl_xor(acc[rr][r], off);
    if (lane == 0) {
        #pragma unroll
        for (int rr = 0; rr < 4; rr++) {
            f32x4 t;
            t[0] = acc[rr][0]; t[1] = acc[rr][1]; t[2] = acc[rr][2]; t[3] = acc[rr][3];
            *(f32x4*)&T[(int64_t)(m0 + rr) * 4] = t;
        }
    }
}

// C[m][n] = act( sum_k A[m][k]*Bm[n][k] + SCALE * sum_r Tlo[m][r]*Blo[aid][n][r] )
// Block tile 256x128, BK=64; 4 waves (2x2), each wave 128x64 (8x4 of 16x16x32
// MFMA). global_load_lds width-16 staging with XOR K-chunk swizzle.
// PART: 0 = partition N across XCDs, 1 = partition M.
// FUSET2: T2[m][r2] += sum_n C[m][n]*A2[aid][r2][n] via atomics.
// NOTE: (256,2) is mandatory — (256,3) caps regs at ~170/wave, spilling the
// 128-AGPR accumulator to scratch (R6: WRITE_SIZE 65->393 MB, 4x slowdown).
template<bool RELU, typename CT, int PART, bool FUSET2>
__global__ __launch_bounds__(256, 2)
void gemm_lora(const bf16* __restrict__ A,    // [M][K] bf16
               const bf16* __restrict__ Bm,   // [N][K] bf16 (torch [out,in])
               CT* __restrict__ C,            // [M][N]
               const float* __restrict__ Tlo, // [M][4]
               const float* __restrict__ Blo, // [NUM][N][4] f32
               const int* __restrict__ adapter,
               const float* __restrict__ A2,  // [NUM][4][N] f32 (FUSET2)
               float* __restrict__ T2,        // [M][4] (FUSET2)
               int M, int N, int K)
{
    __shared__ bf16 smem[256 * 64 + 128 * 64];   // 48 KB
    bf16* sA = smem;                              // [256][64]
    bf16* sB = smem + 256 * 64;                   // [128][64]

    const int tid  = threadIdx.x;
    const int lane = tid & 63;
    const int w    = tid >> 6;
    const int quad = lane >> 4;
    const int l16  = lane & 15;

    // XCD-aware remap (consecutive dispatch ids round-robin across 8 XCDs).
    int bx, by;
    {
        const int Nt = gridDim.x, Mt = gridDim.y;
        const int id = blockIdx.y * Nt + blockIdx.x;
        const int xcd = id & 7, k = id >> 3;
        if (PART == 0) { const int q = Nt >> 3; bx = xcd * q + (k % q); by = k / q; }
        else           { const int q = Mt >> 3; bx = k % Nt; by = xcd * q + (k / Nt); }
    }
    const int nBase = bx * 128;
    const int mBase = by * 256;
    const int wm = (w >> 1) * 128;               // 0 or 128
    const int wn = (w & 1) * 64;                 // 0 or 64

    f32x4 acc[8][4];
    #pragma unroll
    for (int i = 0; i < 8; i++)
        #pragma unroll
        for (int j = 0; j < 4; j++)
            #pragma unroll
            for (int e = 0; e < 4; e++)
                acc[i][j][e] = 0.f;

    const bf16* gA = A  + (int64_t)mBase * K;
    const bf16* gB = Bm + (int64_t)nBase * K;
    const int ldRow  = tid >> 3;                 // 0..31
    const int swzCol = ((tid & 7) ^ ((tid >> 3) & 7)) * 8;

    for (int kt = 0; kt < K; kt += 64) {
        #pragma unroll
        for (int i = 0; i < 8; i++)
            gload_lds16(gA + (int64_t)(i * 32 + ldRow) * K + kt + swzCol,
                        sA + (i * 32 + w * 8) * 64);
        #pragma unroll
        for (int i = 0; i < 4; i++)
            gload_lds16(gB + (int64_t)(i * 32 + ldRow) * K + kt + swzCol,
                        sB + (i * 32 + w * 8) * 64);
        __syncthreads();
        #pragma unroll
        for (int ks = 0; ks < 2; ks++) {
            const int kpos = (((ks * 4 + quad) ^ (l16 & 7))) * 8;
            bf16x8 af[8], bfv[4];
            #pragma unroll
            for (int i = 0; i < 8; i++)
                af[i] = *(const bf16x8*)&sA[(wm + i * 16 + l16) * 64 + kpos];
            #pragma unroll
            for (int j = 0; j < 4; j++)
                bfv[j] = *(const bf16x8*)&sB[(wn + j * 16 + l16) * 64 + kpos];
            #pragma unroll
            for (int i = 0; i < 8; i++)
                #pragma unroll
                for (int j = 0; j < 4; j++)
                    acc[i][j] = __builtin_amdgcn_mfma_f32_16x16x32_bf16(af[i], bfv[j], acc[i][j], 0, 0, 0);
        }
        __syncthreads();
    }

    // Epilogue
    const int aid = adapter[0];
    const float* Ba = Blo + (int64_t)aid * N * 4;

    f32x4 bv[4];
    #pragma unroll
    for (int j = 0; j < 4; j++) {
        const int f = nBase + wn + j * 16 + l16;
        bv[j] = *(const f32x4*)&Ba[(int64_t)f * 4];
    }

    float a2v[4][4];
    if (FUSET2) {
        const float* A2a = A2 + (int64_t)aid * 4 * N;
        #pragma unroll
        for (int j = 0; j < 4; j++) {
            const int f = nBase + wn + j * 16 + l16;
            #pragma unroll
            for (int r2 = 0; r2 < 4; r2++)
                a2v[j][r2] = A2a[(int64_t)r2 * N + f];
        }
    }

    if constexpr (sizeof(CT) == 2) {
        bf16* scratch = smem + w * (64 * 72);
        #pragma unroll
        for (int g = 0; g < 2; g++) {
            #pragma unroll
            for (int mi2 = 0; mi2 < 4; mi2++) {
                const int mi = g * 4 + mi2;
                f32x4 tv[4];
                #pragma unroll
                for (int r = 0; r < 4; r++) {
                    const int m = mBase + wm + mi * 16 + quad * 4 + r;
                    tv[r] = *(const f32x4*)&Tlo[(int64_t)m * 4];
                }
                float tp[4][4];   // [r][r2] partial t2 contributions
                if (FUSET2)
                    #pragma unroll
                    for (int r = 0; r < 4; r++)
                        #pragma unroll
                        for (int r2 = 0; r2 < 4; r2++) tp[r][r2] = 0.f;
                #pragma unroll
                for (int j = 0; j < 4; j++) {
                    #pragma unroll
                    for (int r = 0; r < 4; r++) {
                        const float d = tv[r][0] * bv[j][0] + tv[r][1] * bv[j][1]
                                      + tv[r][2] * bv[j][2] + tv[r][3] * bv[j][3];
                        float v = acc[mi][j][r] + LORA_SCALE * d;
                        if (RELU) v = v > 0.f ? v : 0.f;
                        if (FUSET2)
                            #pragma unroll
                            for (int r2 = 0; r2 < 4; r2++)
                                tp[r][r2] += v * a2v[j][r2];
                        scratch[(mi2 * 16 + quad * 4 + r) * 72 + j * 16 + l16] = (bf16)v;
                    }
                }
                if (FUSET2) {
                    #pragma unroll
                    for (int r = 0; r < 4; r++)
                        #pragma unroll
                        for (int r2 = 0; r2 < 4; r2++)
                            #pragma unroll
                            for (int off = 8; off >= 1; off >>= 1)
                                tp[r][r2] += __shfl_xor(tp[r][r2], off);
                    if (l16 == 0) {
                        #pragma unroll
                        for (int r = 0; r < 4; r++) {
                            const int m = mBase + wm + mi * 16 + quad * 4 + r;
                            #pragma unroll
                            for (int r2 = 0; r2 < 4; r2++)
                                atomicAdd(&T2[(int64_t)m * 4 + r2], tp[r][r2]);
                        }
                    }
                }
            }
            #pragma unroll
            for (int p = 0; p < 8; p++) {
                const int row = p * 8 + (lane >> 3);
                bf16x8 vv = *(const bf16x8*)&scratch[row * 72 + (lane & 7) * 8];
                const int m = mBase + wm + g * 64 + row;
                *(bf16x8*)&C[(int64_t)m * N + nBase + wn + (lane & 7) * 8] = vv;
            }
        }
    } else {
        #pragma unroll
        for (int mi = 0; mi < 8; mi++) {
            f32x4 tv[4];
            #pragma unroll
            for (int r = 0; r < 4; r++) {
                const int m = mBase + wm + mi * 16 + quad * 4 + r;
                tv[r] = *(const f32x4*)&Tlo[(int64_t)m * 4];
            }
            #pragma unroll
            for (int j = 0; j < 4; j++) {
                #pragma unroll
                for (int r = 0; r < 4; r++) {
                    const float d = tv[r][0] * bv[j][0] + tv[r][1] * bv[j][1]
                                  + tv[r][2] * bv[j][2] + tv[r][3] * bv[j][3];
                    float v = acc[mi][j][r] + LORA_SCALE * d;
                    if (RELU) v = v > 0.f ? v : 0.f;
                    const int m = mBase + wm + mi * 16 + quad * 4 + r;
                    C[(int64_t)m * N + nBase + wn + j * 16 + l16] = v;
                }
            }
        }
    }
}

extern "C" void kernel_launch(void* const* d_in, const int* in_sizes, int n_in,
                              void* d_out, int out_size, void* d_ws, size_t ws_size,
                              hipStream_t stream) {
    const float* x  = (const float*)d_in[0];
    const float* W1 = (const float*)d_in[1];
    const float* A1 = (const float*)d_in[2];
    const float* B1 = (const float*)d_in[3];
    const float* W2 = (const float*)d_in[4];
    const float* A2 = (const float*)d_in[5];
    const float* B2 = (const float*)d_in[6];
    const int* adapter = (const int*)d_in[7];
    float* out = (float*)d_out;

    const int M = 16384, D = 1024, F = 4096;

    bf16*  h  = (bf16*)d_ws;                       // M*F bf16 = 128 MiB
    bf16*  xb = h + (size_t)M * F;                 // M*D bf16 =  32 MiB
    bf16*  wb = xb + (size_t)M * D;                // F*D bf16 =   8 MiB (W1b then W2b)
    float* t1 = (float*)(wb + (size_t)F * D);
    float* t2 = t1 + (size_t)M * 4;

    // t1 = x @ A1a^T ; xb = bf16(x) ; t2 = 0
    lora1<<<M / 16, 256, 0, stream>>>(x, A1, adapter, t1, xb, t2, M);
    // wb = bf16(W1)
    cvt_f32_bf16<<<(F * D) / 2048, 256, 0, stream>>>(W1, wb);
    // h = relu(xb @ wb^T + scale * t1 @ B1a^T); t2 += h @ A2a^T (fused)
    dim3 g1(F / 128, M / 256);
    gemm_lora<true, bf16, 0, true><<<g1, 256, 0, stream>>>(
        xb, wb, h, t1, B1, adapter, A2, t2, M, F, D);
    // wb = bf16(W2)
    cvt_f32_bf16<<<(D * F) / 2048, 256, 0, stream>>>(W2, wb);
    // out = h @ wb^T + scale * t2 @ B2a^T  -> f32
    dim3 g2(D / 128, M / 256);
    gemm_lora<false, float, 1, false><<<g2, 256, 0, stream>>>(
        h, wb, out, t2, B2, adapter, nullptr, nullptr, M, D, F);
}

// Round 8
// 443.670 us; speedup vs baseline: 2.0193x; 1.9045x over previous
//
#include <hip/hip_runtime.h>
#include <stdint.h>

typedef __bf16 bf16;
typedef __attribute__((ext_vector_type(8))) __bf16 bf16x8;
typedef __attribute__((ext_vector_type(4))) float f32x4;

#define LORA_SCALE 0.25f

// async global->LDS, 16B per lane. LDS dest is wave-uniform base + lane*16.
__device__ __forceinline__ void gload_lds16(const bf16* g, bf16* l) {
    __builtin_amdgcn_global_load_lds(
        (const __attribute__((address_space(1))) uint32_t*)g,
        (__attribute__((address_space(3))) uint32_t*)l,
        16, 0, 0);
}

__device__ __forceinline__ bf16x8 cvt8(const float* p) {
    f32x4 a = *(const f32x4*)p;
    f32x4 b = *(const f32x4*)(p + 4);
    bf16x8 r;
    r[0] = (bf16)a[0]; r[1] = (bf16)a[1]; r[2] = (bf16)a[2]; r[3] = (bf16)a[3];
    r[4] = (bf16)b[0]; r[5] = (bf16)b[1]; r[6] = (bf16)b[2]; r[7] = (bf16)b[3];
    return r;
}

// Convert W1 (n1 elems) and W2 (n2 elems) f32->bf16 in one launch.
__global__ __launch_bounds__(256)
void cvt_weights(const float* __restrict__ in1, bf16* __restrict__ out1, int n1,
                 const float* __restrict__ in2, bf16* __restrict__ out2, int n2) {
    const int64_t idx = (int64_t)(blockIdx.x * 256 + threadIdx.x) * 8;
    if (idx < n1) *(bf16x8*)&out1[idx] = cvt8(&in1[idx]);
    else          *(bf16x8*)&out2[idx - n1] = cvt8(&in2[idx - n1]);
}

// t1[m][r] = sum_k X[m][k] * Aall[aid][r][k]. 4 rows per wave. Also writes
// Xb = bf16(X). K=1024. Grid: M/16 blocks of 256.
__global__ __launch_bounds__(256)
void lora1(const float* __restrict__ X, const float* __restrict__ Aall,
           const int* __restrict__ adapter, float* __restrict__ T,
           bf16* __restrict__ Xb)
{
    const int K = 1024;
    const int gid = blockIdx.x * 256 + threadIdx.x;
    const int aid = adapter[0];
    const float* Aa = Aall + (int64_t)aid * 4 * K;
    const int wid  = gid >> 6;
    const int lane = threadIdx.x & 63;
    const int m0   = wid * 4;

    float acc[4][4];
    #pragma unroll
    for (int rr = 0; rr < 4; rr++)
        #pragma unroll
        for (int r = 0; r < 4; r++) acc[rr][r] = 0.f;

    #pragma unroll
    for (int it = 0; it < K / 512; it++) {
        const int k = it * 512 + lane * 8;
        float av[4][8];
        #pragma unroll
        for (int r = 0; r < 4; r++) {
            f32x4 a = *(const f32x4*)&Aa[r * K + k];
            f32x4 b = *(const f32x4*)&Aa[r * K + k + 4];
            av[r][0]=a[0]; av[r][1]=a[1]; av[r][2]=a[2]; av[r][3]=a[3];
            av[r][4]=b[0]; av[r][5]=b[1]; av[r][6]=b[2]; av[r][7]=b[3];
        }
        #pragma unroll
        for (int rr = 0; rr < 4; rr++) {
            const float* xp = X + (int64_t)(m0 + rr) * K + k;
            f32x4 a = *(const f32x4*)xp;
            f32x4 b = *(const f32x4*)(xp + 4);
            float xv[8] = {a[0],a[1],a[2],a[3],b[0],b[1],b[2],b[3]};
            bf16x8 xb;
            #pragma unroll
            for (int e = 0; e < 8; e++) xb[e] = (bf16)xv[e];
            *(bf16x8*)&Xb[(int64_t)(m0 + rr) * K + k] = xb;
            #pragma unroll
            for (int r = 0; r < 4; r++)
                #pragma unroll
                for (int e = 0; e < 8; e++)
                    acc[rr][r] += xv[e] * av[r][e];
        }
    }
    #pragma unroll
    for (int rr = 0; rr < 4; rr++)
        #pragma unroll
        for (int r = 0; r < 4; r++)
            #pragma unroll
            for (int off = 32; off >= 1; off >>= 1)
                acc[rr][r] += __shfl_xor(acc[rr][r], off);
    if (lane == 0) {
        #pragma unroll
        for (int rr = 0; rr < 4; rr++) {
            f32x4 t;
            t[0] = acc[rr][0]; t[1] = acc[rr][1]; t[2] = acc[rr][2]; t[3] = acc[rr][3];
            *(f32x4*)&T[(int64_t)(m0 + rr) * 4] = t;
        }
    }
}

// t2[m][r] = sum_p T2p[p][m][r], p < NP. One thread per (m,r).
__global__ __launch_bounds__(256)
void t2_reduce(const float* __restrict__ T2p, float* __restrict__ T2,
               int M, int NP) {
    const int i = blockIdx.x * 256 + threadIdx.x;   // (m*4 + r)
    float s = 0.f;
    for (int p = 0; p < NP; p++) s += T2p[(int64_t)p * M * 4 + i];
    T2[i] = s;
}

// C[m][n] = act( sum_k A[m][k]*Bm[n][k] + SCALE * sum_r Tlo[m][r]*Blo[aid][n][r] )
// Block tile 256x128, BK=64; 4 waves (2x2), each wave 128x64 (8x4 of 16x16x32
// MFMA). global_load_lds width-16 staging with XOR K-chunk swizzle.
// PART: 0 = partition N across XCDs, 1 = partition M.
// FUSET2: T2p[bx*2 + wn-idx][m][r2] = sum over this wave's 64 n of C[m][n]*A2a[r2][n]
//         — plain stores, no atomics (R7: 2M contended atomicAdds cost ~465 µs).
// NOTE: (256,2) mandatory — (256,3) spills the 128-AGPR accumulator (R6).
template<bool RELU, typename CT, int PART, bool FUSET2>
__global__ __launch_bounds__(256, 2)
void gemm_lora(const bf16* __restrict__ A,    // [M][K] bf16
               const bf16* __restrict__ Bm,   // [N][K] bf16 (torch [out,in])
               CT* __restrict__ C,            // [M][N]
               const float* __restrict__ Tlo, // [M][4]
               const float* __restrict__ Blo, // [NUM][N][4] f32
               const int* __restrict__ adapter,
               const float* __restrict__ A2,  // [NUM][4][N] f32 (FUSET2)
               float* __restrict__ T2p,       // [2*Nt][M][4] (FUSET2)
               int M, int N, int K)
{
    __shared__ bf16 smem[256 * 64 + 128 * 64];   // 48 KB
    bf16* sA = smem;                              // [256][64]
    bf16* sB = smem + 256 * 64;                   // [128][64]

    const int tid  = threadIdx.x;
    const int lane = tid & 63;
    const int w    = tid >> 6;
    const int quad = lane >> 4;
    const int l16  = lane & 15;

    // XCD-aware remap (consecutive dispatch ids round-robin across 8 XCDs).
    int bx, by;
    {
        const int Nt = gridDim.x, Mt = gridDim.y;
        const int id = blockIdx.y * Nt + blockIdx.x;
        const int xcd = id & 7, k = id >> 3;
        if (PART == 0) { const int q = Nt >> 3; bx = xcd * q + (k % q); by = k / q; }
        else           { const int q = Mt >> 3; bx = k % Nt; by = xcd * q + (k / Nt); }
    }
    const int nBase = bx * 128;
    const int mBase = by * 256;
    const int wm = (w >> 1) * 128;               // 0 or 128
    const int wn = (w & 1) * 64;                 // 0 or 64

    f32x4 acc[8][4];
    #pragma unroll
    for (int i = 0; i < 8; i++)
        #pragma unroll
        for (int j = 0; j < 4; j++)
            #pragma unroll
            for (int e = 0; e < 4; e++)
                acc[i][j][e] = 0.f;

    const bf16* gA = A  + (int64_t)mBase * K;
    const bf16* gB = Bm + (int64_t)nBase * K;
    const int ldRow  = tid >> 3;                 // 0..31
    const int swzCol = ((tid & 7) ^ ((tid >> 3) & 7)) * 8;

    for (int kt = 0; kt < K; kt += 64) {
        #pragma unroll
        for (int i = 0; i < 8; i++)
            gload_lds16(gA + (int64_t)(i * 32 + ldRow) * K + kt + swzCol,
                        sA + (i * 32 + w * 8) * 64);
        #pragma unroll
        for (int i = 0; i < 4; i++)
            gload_lds16(gB + (int64_t)(i * 32 + ldRow) * K + kt + swzCol,
                        sB + (i * 32 + w * 8) * 64);
        __syncthreads();
        #pragma unroll
        for (int ks = 0; ks < 2; ks++) {
            const int kpos = (((ks * 4 + quad) ^ (l16 & 7))) * 8;
            bf16x8 af[8], bfv[4];
            #pragma unroll
            for (int i = 0; i < 8; i++)
                af[i] = *(const bf16x8*)&sA[(wm + i * 16 + l16) * 64 + kpos];
            #pragma unroll
            for (int j = 0; j < 4; j++)
                bfv[j] = *(const bf16x8*)&sB[(wn + j * 16 + l16) * 64 + kpos];
            #pragma unroll
            for (int i = 0; i < 8; i++)
                #pragma unroll
                for (int j = 0; j < 4; j++)
                    acc[i][j] = __builtin_amdgcn_mfma_f32_16x16x32_bf16(af[i], bfv[j], acc[i][j], 0, 0, 0);
        }
        __syncthreads();
    }

    // Epilogue
    const int aid = adapter[0];
    const float* Ba = Blo + (int64_t)aid * N * 4;

    f32x4 bv[4];
    #pragma unroll
    for (int j = 0; j < 4; j++) {
        const int f = nBase + wn + j * 16 + l16;
        bv[j] = *(const f32x4*)&Ba[(int64_t)f * 4];
    }

    float a2v[4][4];
    if (FUSET2) {
        const float* A2a = A2 + (int64_t)aid * 4 * N;
        #pragma unroll
        for (int j = 0; j < 4; j++) {
            const int f = nBase + wn + j * 16 + l16;
            #pragma unroll
            for (int r2 = 0; r2 < 4; r2++)
                a2v[j][r2] = A2a[(int64_t)r2 * N + f];
        }
    }
    float* T2row = FUSET2 ? T2p + ((int64_t)(bx * 2 + (w & 1)) * M) * 4 : nullptr;

    if constexpr (sizeof(CT) == 2) {
        bf16* scratch = smem + w * (64 * 72);
        #pragma unroll
        for (int g = 0; g < 2; g++) {
            #pragma unroll
            for (int mi2 = 0; mi2 < 4; mi2++) {
                const int mi = g * 4 + mi2;
                f32x4 tv[4];
                #pragma unroll
                for (int r = 0; r < 4; r++) {
                    const int m = mBase + wm + mi * 16 + quad * 4 + r;
                    tv[r] = *(const f32x4*)&Tlo[(int64_t)m * 4];
                }
                float tp[4][4];   // [r][r2] partial t2 contributions
                if (FUSET2)
                    #pragma unroll
                    for (int r = 0; r < 4; r++)
                        #pragma unroll
                        for (int r2 = 0; r2 < 4; r2++) tp[r][r2] = 0.f;
                #pragma unroll
                for (int j = 0; j < 4; j++) {
                    #pragma unroll
                    for (int r = 0; r < 4; r++) {
                        const float d = tv[r][0] * bv[j][0] + tv[r][1] * bv[j][1]
                                      + tv[r][2] * bv[j][2] + tv[r][3] * bv[j][3];
                        float v = acc[mi][j][r] + LORA_SCALE * d;
                        if (RELU) v = v > 0.f ? v : 0.f;
                        if (FUSET2)
                            #pragma unroll
                            for (int r2 = 0; r2 < 4; r2++)
                                tp[r][r2] += v * a2v[j][r2];
                        scratch[(mi2 * 16 + quad * 4 + r) * 72 + j * 16 + l16] = (bf16)v;
                    }
                }
                if (FUSET2) {
                    #pragma unroll
                    for (int r = 0; r < 4; r++)
                        #pragma unroll
                        for (int r2 = 0; r2 < 4; r2++)
                            #pragma unroll
                            for (int off = 8; off >= 1; off >>= 1)
                                tp[r][r2] += __shfl_xor(tp[r][r2], off);
                    if (l16 == 0) {
                        #pragma unroll
                        for (int r = 0; r < 4; r++) {
                            const int m = mBase + wm + mi * 16 + quad * 4 + r;
                            f32x4 o;
                            o[0] = tp[r][0]; o[1] = tp[r][1];
                            o[2] = tp[r][2]; o[3] = tp[r][3];
                            *(f32x4*)&T2row[(int64_t)m * 4] = o;   // plain store
                        }
                    }
                }
            }
            #pragma unroll
            for (int p = 0; p < 8; p++) {
                const int row = p * 8 + (lane >> 3);
                bf16x8 vv = *(const bf16x8*)&scratch[row * 72 + (lane & 7) * 8];
                const int m = mBase + wm + g * 64 + row;
                *(bf16x8*)&C[(int64_t)m * N + nBase + wn + (lane & 7) * 8] = vv;
            }
        }
    } else {
        #pragma unroll
        for (int mi = 0; mi < 8; mi++) {
            f32x4 tv[4];
            #pragma unroll
            for (int r = 0; r < 4; r++) {
                const int m = mBase + wm + mi * 16 + quad * 4 + r;
                tv[r] = *(const f32x4*)&Tlo[(int64_t)m * 4];
            }
            #pragma unroll
            for (int j = 0; j < 4; j++) {
                #pragma unroll
                for (int r = 0; r < 4; r++) {
                    const float d = tv[r][0] * bv[j][0] + tv[r][1] * bv[j][1]
                                  + tv[r][2] * bv[j][2] + tv[r][3] * bv[j][3];
                    float v = acc[mi][j][r] + LORA_SCALE * d;
                    if (RELU) v = v > 0.f ? v : 0.f;
                    const int m = mBase + wm + mi * 16 + quad * 4 + r;
                    C[(int64_t)m * N + nBase + wn + j * 16 + l16] = v;
                }
            }
        }
    }
}

extern "C" void kernel_launch(void* const* d_in, const int* in_sizes, int n_in,
                              void* d_out, int out_size, void* d_ws, size_t ws_size,
                              hipStream_t stream) {
    const float* x  = (const float*)d_in[0];
    const float* W1 = (const float*)d_in[1];
    const float* A1 = (const float*)d_in[2];
    const float* B1 = (const float*)d_in[3];
    const float* W2 = (const float*)d_in[4];
    const float* A2 = (const float*)d_in[5];
    const float* B2 = (const float*)d_in[6];
    const int* adapter = (const int*)d_in[7];
    float* out = (float*)d_out;

    const int M = 16384, D = 1024, F = 4096;
    const int Nt1 = F / 128;                       // 32 N-tiles in GEMM1

    // ws layout (~192.5 MiB):
    bf16*  h   = (bf16*)d_ws;                      // M*F bf16 = 128 MiB
    bf16*  xb  = h + (size_t)M * F;                // M*D bf16 =  32 MiB
    bf16*  wb1 = xb + (size_t)M * D;               // F*D bf16 =   8 MiB
    bf16*  wb2 = wb1 + (size_t)F * D;              // D*F bf16 =   8 MiB
    float* t1  = (float*)(wb2 + (size_t)D * F);    // M*4 f32
    float* t2  = t1 + (size_t)M * 4;               // M*4 f32
    float* t2p = t2 + (size_t)M * 4;               // 64*M*4 f32 = 16 MiB

    // t1 = x @ A1a^T ; xb = bf16(x)
    lora1<<<M / 16, 256, 0, stream>>>(x, A1, adapter, t1, xb);
    // wb1 = bf16(W1), wb2 = bf16(W2)
    cvt_weights<<<(2 * F * D) / 2048, 256, 0, stream>>>(W1, wb1, F * D, W2, wb2, D * F);
    // h = relu(xb @ wb1^T + scale * t1 @ B1a^T); t2p partials (fused, no atomics)
    dim3 g1(Nt1, M / 256);
    gemm_lora<true, bf16, 0, true><<<g1, 256, 0, stream>>>(
        xb, wb1, h, t1, B1, adapter, A2, t2p, M, F, D);
    // t2 = reduce(t2p)
    t2_reduce<<<(M * 4) / 256, 256, 0, stream>>>(t2p, t2, M, 2 * Nt1);
    // out = h @ wb2^T + scale * t2 @ B2a^T  -> f32
    dim3 g2(D / 128, M / 256);
    gemm_lora<false, float, 1, false><<<g2, 256, 0, stream>>>(
        h, wb2, out, t2, B2, adapter, nullptr, nullptr, M, D, F);
}